// Round 2
// baseline (930.015 us; speedup 1.0000x reference)
//
#include <hip/hip_runtime.h>

#define BB 64
#define TT 2048
#define HH 512
#define NROWS (BB * TT)

#define NLOG2E  (-1.4426950408889634f)
#define N2LOG2E (-2.8853900817779268f)

// sigmoid(x) where zs = -x*log2(e):   1/(1+2^zs)
static __device__ __forceinline__ float sigm2(float zs) {
  return __builtin_amdgcn_rcpf(1.0f + __builtin_amdgcn_exp2f(zs));
}
// tanh(x) where zs = -2x*log2(e):     2/(1+2^zs) - 1
static __device__ __forceinline__ float tanh2(float zs) {
  return fmaf(2.0f, __builtin_amdgcn_rcpf(1.0f + __builtin_amdgcn_exp2f(zs)), -1.0f);
}

static __device__ __forceinline__ float dot4(float4 a, float4 b) {
  return fmaf(a.x, b.x, fmaf(a.y, b.y, fmaf(a.z, b.z, a.w * b.w)));
}

// Kernel A: projections + where(worry) + LSTM input pre-activations.
// One wave per (b,t) row: 64 lanes x 8 floats = 512 columns, coalesced.
// ws row layout (16 floats): u1[0..7] (p1 gate pre-acts, pre-scaled),
// u2[0..3] (p2 gate pre-acts, pre-scaled), d0, d1 (post-where noworry det), pad2.
__global__ __launch_bounds__(256) void proj_kernel(
    const float* __restrict__ x, const int* __restrict__ worry,
    const float* __restrict__ Wnw, const float* __restrict__ bnw,
    const float* __restrict__ Ww,  const float* __restrict__ bw,
    const float* __restrict__ Wih1, const float* __restrict__ bih1, const float* __restrict__ bhh1,
    const float* __restrict__ Wih2, const float* __restrict__ bih2, const float* __restrict__ bhh2,
    float* __restrict__ out_nw, float* __restrict__ ws)
{
  const int lane = threadIdx.x & 63;
  const int wid  = blockIdx.x * (blockDim.x >> 6) + (threadIdx.x >> 6);
  const int nwv  = gridDim.x * (blockDim.x >> 6);
  const int cb   = lane * 4;

  // per-lane weight slices (two 256-col halves, 2 rows each matrix)
  const float4 wa0 = *(const float4*)(Wnw + cb);
  const float4 wb0 = *(const float4*)(Wnw + 256 + cb);
  const float4 wa1 = *(const float4*)(Wnw + 512 + cb);
  const float4 wb1 = *(const float4*)(Wnw + 768 + cb);
  const float4 va0 = *(const float4*)(Ww  + cb);
  const float4 vb0 = *(const float4*)(Ww  + 256 + cb);
  const float4 va1 = *(const float4*)(Ww  + 512 + cb);
  const float4 vb1 = *(const float4*)(Ww  + 768 + cb);

  for (int r = wid; r < NROWS; r += nwv) {
    const float* xr = x + (size_t)r * HH;
    const float4 xa = *(const float4*)(xr + cb);
    const float4 xb = *(const float4*)(xr + 256 + cb);

    float a0 = dot4(xa, wa0) + dot4(xb, wb0);
    float a1 = dot4(xa, wa1) + dot4(xb, wb1);
    float a2 = dot4(xa, va0) + dot4(xb, vb0);
    float a3 = dot4(xa, va1) + dot4(xb, vb1);

#pragma unroll
    for (int off = 32; off > 0; off >>= 1) {
      a0 += __shfl_xor(a0, off, 64);
      a1 += __shfl_xor(a1, off, 64);
      a2 += __shfl_xor(a2, off, 64);
      a3 += __shfl_xor(a3, off, 64);
    }

    if (lane == 0) {
      const float n0 = a0 + bnw[0], n1 = a1 + bnw[1];
      const float w0 = a2 + bw[0],  w1 = a3 + bw[1];
      const bool wt = worry[r] != 0;   // int32! (harness passes bool as int)
      const float d0 = wt ? w0 : n0;
      const float d1 = wt ? w1 : n1;
      *(float2*)(out_nw + (size_t)r * 2) = make_float2(d0, d1);

      float u[12];
#pragma unroll
      for (int k = 0; k < 8; ++k) {  // p1 gates: rows 0-1=i, 2-3=f, 4-5=g, 6-7=o
        const float s = (k == 4 || k == 5) ? N2LOG2E : NLOG2E;
        u[k] = s * (bih1[k] + bhh1[k] + fmaf(Wih1[2 * k], d0, Wih1[2 * k + 1] * d1));
      }
#pragma unroll
      for (int k = 0; k < 4; ++k) {  // p2 gates: 0=i,1=f,2=g,3=o ; input = worry_det
        const float s = (k == 2) ? N2LOG2E : NLOG2E;
        u[8 + k] = s * (bih2[k] + bhh2[k] + fmaf(Wih2[2 * k], w0, Wih2[2 * k + 1] * w1));
      }
      float* wp = ws + (size_t)r * 16;
      *(float4*)(wp)      = make_float4(u[0], u[1], u[2],  u[3]);
      *(float4*)(wp + 4)  = make_float4(u[4], u[5], u[6],  u[7]);
      *(float4*)(wp + 8)  = make_float4(u[8], u[9], u[10], u[11]);
      *(float2*)(wp + 12) = make_float2(d0, d1);
    }
  }
}

// Kernel B: both recurrences + fused adjust output. One lane per batch element.
__global__ __launch_bounds__(64) void lstm_kernel(
    const float* __restrict__ ws, const int* __restrict__ lengths,
    const float* __restrict__ Whh1, const float* __restrict__ Whh2,
    float* __restrict__ out_adj)
{
  const int b = threadIdx.x;  // 0..63

  float A[8][2];
#pragma unroll
  for (int k = 0; k < 8; ++k) {
    const float s = (k == 4 || k == 5) ? N2LOG2E : NLOG2E;
    A[k][0] = s * Whh1[2 * k];
    A[k][1] = s * Whh1[2 * k + 1];
  }
  float A2[4];
#pragma unroll
  for (int k = 0; k < 4; ++k) {
    const float s = (k == 2) ? N2LOG2E : NLOG2E;
    A2[k] = s * Whh2[k];
  }

  const int len = lengths[b];
  const float* p = ws + (size_t)b * TT * 16;
  float* o = out_adj + (size_t)b * TT * 2;

  float h0 = 0.f, h1 = 0.f, c0 = 0.f, c1 = 0.f;  // p1 state (H=2)
  float h2 = 0.f, c2 = 0.f;                       // p2 state (H=1)

  float4 ua = *(const float4*)(p);
  float4 ub = *(const float4*)(p + 4);
  float4 uc = *(const float4*)(p + 8);
  float2 nw = *(const float2*)(p + 12);

  for (int t = 0; t < TT; ++t) {
    const float* pn = (t + 1 < TT) ? (p + 16) : p;
    const float4 nua = *(const float4*)(pn);
    const float4 nub = *(const float4*)(pn + 4);
    const float4 nuc = *(const float4*)(pn + 8);
    const float2 nnw = *(const float2*)(pn + 12);

    // p1: z = u + Whh_s . h  (already scaled for exp2-based activations)
    const float zi0 = ua.x + fmaf(A[0][0], h0, A[0][1] * h1);
    const float zi1 = ua.y + fmaf(A[1][0], h0, A[1][1] * h1);
    const float zf0 = ua.z + fmaf(A[2][0], h0, A[2][1] * h1);
    const float zf1 = ua.w + fmaf(A[3][0], h0, A[3][1] * h1);
    const float zg0 = ub.x + fmaf(A[4][0], h0, A[4][1] * h1);
    const float zg1 = ub.y + fmaf(A[5][0], h0, A[5][1] * h1);
    const float zo0 = ub.z + fmaf(A[6][0], h0, A[6][1] * h1);
    const float zo1 = ub.w + fmaf(A[7][0], h0, A[7][1] * h1);

    const float si0 = sigm2(zi0), si1 = sigm2(zi1);
    const float sf0 = sigm2(zf0), sf1 = sigm2(zf1);
    const float tg0 = tanh2(zg0), tg1 = tanh2(zg1);
    const float so0 = sigm2(zo0), so1 = sigm2(zo1);

    c0 = fmaf(sf0, c0, si0 * tg0);
    c1 = fmaf(sf1, c1, si1 * tg1);
    h0 = so0 * tanh2(N2LOG2E * c0);
    h1 = so1 * tanh2(N2LOG2E * c1);

    // p2 (H=1)
    const float yi = uc.x + A2[0] * h2;
    const float yf = uc.y + A2[1] * h2;
    const float yg = uc.z + A2[2] * h2;
    const float yo = uc.w + A2[3] * h2;
    c2 = fmaf(sigm2(yf), c2, sigm2(yi) * tanh2(yg));
    h2 = sigm2(yo) * tanh2(N2LOG2E * c2);

    // adjust = nw - p1 + p2 (masked: past length p1=p2=0)
    const bool v = t < len;
    const float a0 = v ? (nw.x - h0 + h2) : nw.x;
    const float a1 = v ? (nw.y - h1 + h2) : nw.y;
    *(float2*)o = make_float2(a0, a1);

    o += 2;
    p = pn;
    ua = nua; ub = nub; uc = nuc; nw = nnw;
  }
}

extern "C" void kernel_launch(void* const* d_in, const int* in_sizes, int n_in,
                              void* d_out, int out_size, void* d_ws, size_t ws_size,
                              hipStream_t stream) {
  const float* x            = (const float*)d_in[0];
  const int* wt             = (const int*)d_in[1];
  const int* lengths        = (const int*)d_in[2];
  const float* Wnw          = (const float*)d_in[3];
  const float* bnw          = (const float*)d_in[4];
  const float* Ww           = (const float*)d_in[5];
  const float* bw           = (const float*)d_in[6];
  const float* Wih1         = (const float*)d_in[7];
  const float* Whh1         = (const float*)d_in[8];
  const float* bih1         = (const float*)d_in[9];
  const float* bhh1         = (const float*)d_in[10];
  const float* Wih2         = (const float*)d_in[11];
  const float* Whh2         = (const float*)d_in[12];
  const float* bih2         = (const float*)d_in[13];
  const float* bhh2         = (const float*)d_in[14];

  float* out_nw  = (float*)d_out;                       // [B,T,2]
  float* out_adj = (float*)d_out + (size_t)NROWS * 2;   // [B,T,2]
  float* ws      = (float*)d_ws;                        // [B,T,16] floats = 8 MB

  proj_kernel<<<1024, 256, 0, stream>>>(x, wt, Wnw, bnw, Ww, bw,
                                        Wih1, bih1, bhh1, Wih2, bih2, bhh2,
                                        out_nw, ws);
  lstm_kernel<<<1, 64, 0, stream>>>(ws, lengths, Whh1, Whh2, out_adj);
}

// Round 3
// 537.693 us; speedup vs baseline: 1.7296x; 1.7296x over previous
//
#include <hip/hip_runtime.h>

#define BB 64
#define TT 2048
#define HH 512
#define NROWS (BB * TT)
#define DP 8   // lstm software-pipeline depth (steps of prefetch)

#define NLOG2E  (-1.4426950408889634f)
#define N2LOG2E (-2.8853900817779268f)

// sigmoid(x) where zs = -x*log2(e):   1/(1+2^zs)
static __device__ __forceinline__ float sigm2(float zs) {
  return __builtin_amdgcn_rcpf(1.0f + __builtin_amdgcn_exp2f(zs));
}
// tanh(x) where zs = -2x*log2(e):     2/(1+2^zs) - 1
static __device__ __forceinline__ float tanh2(float zs) {
  return fmaf(2.0f, __builtin_amdgcn_rcpf(1.0f + __builtin_amdgcn_exp2f(zs)), -1.0f);
}

static __device__ __forceinline__ float dot4(float4 a, float4 b) {
  return fmaf(a.x, b.x, fmaf(a.y, b.y, fmaf(a.z, b.z, a.w * b.w)));
}

// Kernel A: projections + where(worry) + LSTM input pre-activations.
// One wave per (b,t) row: 64 lanes x 8 floats = 512 columns, coalesced.
// ws layout is TRANSPOSED for kernel B's benefit: [T][B][16 floats]:
// u1[0..7] (p1 gate pre-acts, pre-scaled), u2[0..3] (p2, pre-scaled), d0, d1, pad2.
__global__ __launch_bounds__(256) void proj_kernel(
    const float* __restrict__ x, const int* __restrict__ worry,
    const float* __restrict__ Wnw, const float* __restrict__ bnw,
    const float* __restrict__ Ww,  const float* __restrict__ bw,
    const float* __restrict__ Wih1, const float* __restrict__ bih1, const float* __restrict__ bhh1,
    const float* __restrict__ Wih2, const float* __restrict__ bih2, const float* __restrict__ bhh2,
    float* __restrict__ out_nw, float* __restrict__ ws)
{
  const int lane = threadIdx.x & 63;
  const int wid  = blockIdx.x * (blockDim.x >> 6) + (threadIdx.x >> 6);
  const int nwv  = gridDim.x * (blockDim.x >> 6);
  const int cb   = lane * 4;

  // per-lane weight slices (two 256-col halves, 2 rows each matrix)
  const float4 wa0 = *(const float4*)(Wnw + cb);
  const float4 wb0 = *(const float4*)(Wnw + 256 + cb);
  const float4 wa1 = *(const float4*)(Wnw + 512 + cb);
  const float4 wb1 = *(const float4*)(Wnw + 768 + cb);
  const float4 va0 = *(const float4*)(Ww  + cb);
  const float4 vb0 = *(const float4*)(Ww  + 256 + cb);
  const float4 va1 = *(const float4*)(Ww  + 512 + cb);
  const float4 vb1 = *(const float4*)(Ww  + 768 + cb);

  for (int r = wid; r < NROWS; r += nwv) {
    const float* xr = x + (size_t)r * HH;
    const float4 xa = *(const float4*)(xr + cb);
    const float4 xb = *(const float4*)(xr + 256 + cb);

    float a0 = dot4(xa, wa0) + dot4(xb, wb0);
    float a1 = dot4(xa, wa1) + dot4(xb, wb1);
    float a2 = dot4(xa, va0) + dot4(xb, vb0);
    float a3 = dot4(xa, va1) + dot4(xb, vb1);

#pragma unroll
    for (int off = 32; off > 0; off >>= 1) {
      a0 += __shfl_xor(a0, off, 64);
      a1 += __shfl_xor(a1, off, 64);
      a2 += __shfl_xor(a2, off, 64);
      a3 += __shfl_xor(a3, off, 64);
    }

    if (lane == 0) {
      const float n0 = a0 + bnw[0], n1 = a1 + bnw[1];
      const float w0 = a2 + bw[0],  w1 = a3 + bw[1];
      const bool wt = worry[r] != 0;   // int32 (harness passes bool as int)
      const float d0 = wt ? w0 : n0;
      const float d1 = wt ? w1 : n1;
      *(float2*)(out_nw + (size_t)r * 2) = make_float2(d0, d1);

      float u[12];
#pragma unroll
      for (int k = 0; k < 8; ++k) {  // p1 gates: rows 0-1=i, 2-3=f, 4-5=g, 6-7=o
        const float s = (k == 4 || k == 5) ? N2LOG2E : NLOG2E;
        u[k] = s * (bih1[k] + bhh1[k] + fmaf(Wih1[2 * k], d0, Wih1[2 * k + 1] * d1));
      }
#pragma unroll
      for (int k = 0; k < 4; ++k) {  // p2 gates: 0=i,1=f,2=g,3=o ; input = worry_det
        const float s = (k == 2) ? N2LOG2E : NLOG2E;
        u[8 + k] = s * (bih2[k] + bhh2[k] + fmaf(Wih2[2 * k], w0, Wih2[2 * k + 1] * w1));
      }
      // transposed: row r = b*TT + t  ->  ws[(t*BB + b)*16]
      float* wp = ws + (((size_t)(r & (TT - 1)) * BB) + (r >> 11)) * 16;
      *(float4*)(wp)      = make_float4(u[0], u[1], u[2],  u[3]);
      *(float4*)(wp + 4)  = make_float4(u[4], u[5], u[6],  u[7]);
      *(float4*)(wp + 8)  = make_float4(u[8], u[9], u[10], u[11]);
      *(float4*)(wp + 12) = make_float4(d0, d1, 0.f, 0.f);
    }
  }
}

// Kernel B: both recurrences + fused adjust output. One lane per batch element.
// ws is [T][B][16]: per step the wave reads one contiguous 4KB block (coalesced).
// 8-step fully-unrolled register pipeline hides the ~600-900cy memory latency.
__global__ __launch_bounds__(64) void lstm_kernel(
    const float* __restrict__ ws, const int* __restrict__ lengths,
    const float* __restrict__ Whh1, const float* __restrict__ Whh2,
    float* __restrict__ out_adj)
{
  const int b = threadIdx.x;  // 0..63

  float A[8][2];
#pragma unroll
  for (int k = 0; k < 8; ++k) {
    const float s = (k == 4 || k == 5) ? N2LOG2E : NLOG2E;
    A[k][0] = s * Whh1[2 * k];
    A[k][1] = s * Whh1[2 * k + 1];
  }
  float A2[4];
#pragma unroll
  for (int k = 0; k < 4; ++k) {
    const float s = (k == 2) ? N2LOG2E : NLOG2E;
    A2[k] = s * Whh2[k];
  }

  const int len = lengths[b];
  const float* base = ws + b * 16;          // lane's column in the [T][B][16] grid
  float* o = out_adj + (size_t)b * TT * 2;

  float h0 = 0.f, h1 = 0.f, c0 = 0.f, c1 = 0.f;  // p1 state (H=2)
  float h2 = 0.f, c2 = 0.f;                       // p2 state (H=1)

  // register pipeline: DP steps in flight, 4 float4 each (static indices only)
  float4 qa[DP], qb[DP], qc[DP], qd[DP];
#pragma unroll
  for (int j = 0; j < DP; ++j) {
    const float* p = base + (size_t)j * (16 * BB);
    qa[j] = *(const float4*)(p);
    qb[j] = *(const float4*)(p + 4);
    qc[j] = *(const float4*)(p + 8);
    qd[j] = *(const float4*)(p + 12);
  }

  for (int t0 = 0; t0 < TT; t0 += DP) {
#pragma unroll
    for (int j = 0; j < DP; ++j) {
      const int t = t0 + j;
      const float4 ua = qa[j], ub = qb[j], uc = qc[j], nw = qd[j];

      // issue prefetch for step t+DP into this slot (clamped; step 0 is harmless)
      {
        const int tn = t + DP;
        const float* pn = base + (size_t)(tn < TT ? tn : 0) * (16 * BB);
        qa[j] = *(const float4*)(pn);
        qb[j] = *(const float4*)(pn + 4);
        qc[j] = *(const float4*)(pn + 8);
        qd[j] = *(const float4*)(pn + 12);
      }

      // p1: z = fma(A0,h0, fma(A1,h1, u))  (pre-scaled for exp2 activations)
      const float zi0 = fmaf(A[0][0], h0, fmaf(A[0][1], h1, ua.x));
      const float zi1 = fmaf(A[1][0], h0, fmaf(A[1][1], h1, ua.y));
      const float zf0 = fmaf(A[2][0], h0, fmaf(A[2][1], h1, ua.z));
      const float zf1 = fmaf(A[3][0], h0, fmaf(A[3][1], h1, ua.w));
      const float zg0 = fmaf(A[4][0], h0, fmaf(A[4][1], h1, ub.x));
      const float zg1 = fmaf(A[5][0], h0, fmaf(A[5][1], h1, ub.y));
      const float zo0 = fmaf(A[6][0], h0, fmaf(A[6][1], h1, ub.z));
      const float zo1 = fmaf(A[7][0], h0, fmaf(A[7][1], h1, ub.w));

      const float si0 = sigm2(zi0), si1 = sigm2(zi1);
      const float sf0 = sigm2(zf0), sf1 = sigm2(zf1);
      const float tg0 = tanh2(zg0), tg1 = tanh2(zg1);
      const float so0 = sigm2(zo0), so1 = sigm2(zo1);

      c0 = fmaf(sf0, c0, si0 * tg0);
      c1 = fmaf(sf1, c1, si1 * tg1);
      h0 = so0 * tanh2(N2LOG2E * c0);
      h1 = so1 * tanh2(N2LOG2E * c1);

      // p2 (H=1)
      const float yi = fmaf(A2[0], h2, uc.x);
      const float yf = fmaf(A2[1], h2, uc.y);
      const float yg = fmaf(A2[2], h2, uc.z);
      const float yo = fmaf(A2[3], h2, uc.w);
      c2 = fmaf(sigm2(yf), c2, sigm2(yi) * tanh2(yg));
      h2 = sigm2(yo) * tanh2(N2LOG2E * c2);

      // adjust = nw - p1 + p2 (masked: past length p1=p2=0)
      const bool v = t < len;
      const float a0 = v ? (nw.x - h0 + h2) : nw.x;
      const float a1 = v ? (nw.y - h1 + h2) : nw.y;
      *(float2*)(o + (size_t)t * 2) = make_float2(a0, a1);
    }
  }
}

extern "C" void kernel_launch(void* const* d_in, const int* in_sizes, int n_in,
                              void* d_out, int out_size, void* d_ws, size_t ws_size,
                              hipStream_t stream) {
  const float* x            = (const float*)d_in[0];
  const int* wt             = (const int*)d_in[1];
  const int* lengths        = (const int*)d_in[2];
  const float* Wnw          = (const float*)d_in[3];
  const float* bnw          = (const float*)d_in[4];
  const float* Ww           = (const float*)d_in[5];
  const float* bw           = (const float*)d_in[6];
  const float* Wih1         = (const float*)d_in[7];
  const float* Whh1         = (const float*)d_in[8];
  const float* bih1         = (const float*)d_in[9];
  const float* bhh1         = (const float*)d_in[10];
  const float* Wih2         = (const float*)d_in[11];
  const float* Whh2         = (const float*)d_in[12];
  const float* bih2         = (const float*)d_in[13];
  const float* bhh2         = (const float*)d_in[14];

  float* out_nw  = (float*)d_out;                       // [B,T,2]
  float* out_adj = (float*)d_out + (size_t)NROWS * 2;   // [B,T,2]
  float* ws      = (float*)d_ws;                        // [T][B][16] floats = 8 MB

  proj_kernel<<<1024, 256, 0, stream>>>(x, wt, Wnw, bnw, Ww, bw,
                                        Wih1, bih1, bhh1, Wih2, bih2, bhh2,
                                        out_nw, ws);
  lstm_kernel<<<1, 64, 0, stream>>>(ws, lengths, Whh1, Whh2, out_adj);
}

// Round 5
// 526.278 us; speedup vs baseline: 1.7672x; 1.0217x over previous
//
#include <hip/hip_runtime.h>

#define BB 64
#define TT 2048
#define HH 512
#define NROWS (BB * TT)
#define CH 4   // steps per chunk; double-buffered => prefetch distance = 4 steps

#define NLOG2E  (-1.4426950408889634f)
#define N2LOG2E (-2.8853900817779268f)

typedef float f32x4 __attribute__((ext_vector_type(4)));

// sigmoid(x) where zs = -x*log2(e):   1/(1+2^zs)
static __device__ __forceinline__ float sigm2(float zs) {
  return __builtin_amdgcn_rcpf(1.0f + __builtin_amdgcn_exp2f(zs));
}
// tanh(x) where zs = -2x*log2(e):     2/(1+2^zs) - 1
static __device__ __forceinline__ float tanh2(float zs) {
  return fmaf(2.0f, __builtin_amdgcn_rcpf(1.0f + __builtin_amdgcn_exp2f(zs)), -1.0f);
}

static __device__ __forceinline__ float dot4(float4 a, float4 b) {
  return fmaf(a.x, b.x, fmaf(a.y, b.y, fmaf(a.z, b.z, a.w * b.w)));
}

// Kernel A: projections + where(worry) + LSTM input pre-activations.
// One wave per (b,t) row: 64 lanes x 8 floats = 512 columns, coalesced.
// ws layout TRANSPOSED for kernel B: [T][B][16 floats]:
// u1[0..7] (p1 gate pre-acts, pre-scaled), u2[0..3] (p2, pre-scaled), d0, d1, pad2.
__global__ __launch_bounds__(256) void proj_kernel(
    const float* __restrict__ x, const int* __restrict__ worry,
    const float* __restrict__ Wnw, const float* __restrict__ bnw,
    const float* __restrict__ Ww,  const float* __restrict__ bw,
    const float* __restrict__ Wih1, const float* __restrict__ bih1, const float* __restrict__ bhh1,
    const float* __restrict__ Wih2, const float* __restrict__ bih2, const float* __restrict__ bhh2,
    float* __restrict__ out_nw, float* __restrict__ ws)
{
  const int lane = threadIdx.x & 63;
  const int wid  = blockIdx.x * (blockDim.x >> 6) + (threadIdx.x >> 6);
  const int nwv  = gridDim.x * (blockDim.x >> 6);
  const int cb   = lane * 4;

  const float4 wa0 = *(const float4*)(Wnw + cb);
  const float4 wb0 = *(const float4*)(Wnw + 256 + cb);
  const float4 wa1 = *(const float4*)(Wnw + 512 + cb);
  const float4 wb1 = *(const float4*)(Wnw + 768 + cb);
  const float4 va0 = *(const float4*)(Ww  + cb);
  const float4 vb0 = *(const float4*)(Ww  + 256 + cb);
  const float4 va1 = *(const float4*)(Ww  + 512 + cb);
  const float4 vb1 = *(const float4*)(Ww  + 768 + cb);

  for (int r = wid; r < NROWS; r += nwv) {
    const float* xr = x + (size_t)r * HH;
    const float4 xa = *(const float4*)(xr + cb);
    const float4 xb = *(const float4*)(xr + 256 + cb);

    float a0 = dot4(xa, wa0) + dot4(xb, wb0);
    float a1 = dot4(xa, wa1) + dot4(xb, wb1);
    float a2 = dot4(xa, va0) + dot4(xb, vb0);
    float a3 = dot4(xa, va1) + dot4(xb, vb1);

#pragma unroll
    for (int off = 32; off > 0; off >>= 1) {
      a0 += __shfl_xor(a0, off, 64);
      a1 += __shfl_xor(a1, off, 64);
      a2 += __shfl_xor(a2, off, 64);
      a3 += __shfl_xor(a3, off, 64);
    }

    if (lane == 0) {
      const float n0 = a0 + bnw[0], n1 = a1 + bnw[1];
      const float w0 = a2 + bw[0],  w1 = a3 + bw[1];
      const bool wt = worry[r] != 0;   // int32 (harness passes bool as int)
      const float d0 = wt ? w0 : n0;
      const float d1 = wt ? w1 : n1;
      *(float2*)(out_nw + (size_t)r * 2) = make_float2(d0, d1);

      float u[12];
#pragma unroll
      for (int k = 0; k < 8; ++k) {  // p1 gates: rows 0-1=i, 2-3=f, 4-5=g, 6-7=o
        const float s = (k == 4 || k == 5) ? N2LOG2E : NLOG2E;
        u[k] = s * (bih1[k] + bhh1[k] + fmaf(Wih1[2 * k], d0, Wih1[2 * k + 1] * d1));
      }
#pragma unroll
      for (int k = 0; k < 4; ++k) {  // p2 gates: 0=i,1=f,2=g,3=o ; input = worry_det
        const float s = (k == 2) ? N2LOG2E : NLOG2E;
        u[8 + k] = s * (bih2[k] + bhh2[k] + fmaf(Wih2[2 * k], w0, Wih2[2 * k + 1] * w1));
      }
      // transposed: row r = b*TT + t  ->  ws[(t*BB + b)*16]
      float* wp = ws + (((size_t)(r & (TT - 1)) * BB) + (r >> 11)) * 16;
      *(float4*)(wp)      = make_float4(u[0], u[1], u[2],  u[3]);
      *(float4*)(wp + 4)  = make_float4(u[4], u[5], u[6],  u[7]);
      *(float4*)(wp + 8)  = make_float4(u[8], u[9], u[10], u[11]);
      *(float4*)(wp + 12) = make_float4(d0, d1, 0.f, 0.f);
    }
  }
}

// one LSTM step for both recurrences + fused masked adjust-store
static __device__ __forceinline__ void lstm_step(
    const f32x4 ua, const f32x4 ub, const f32x4 uc, const f32x4 nw,
    const float A[8][2], const float A2[4],
    float& h0, float& h1, float& c0, float& c1, float& h2, float& c2,
    const int t, const int len, float* __restrict__ o)
{
  // p1: z = fma(A0,h0, fma(A1,h1, u))  (pre-scaled for exp2 activations)
  const float zi0 = fmaf(A[0][0], h0, fmaf(A[0][1], h1, ua[0]));
  const float zi1 = fmaf(A[1][0], h0, fmaf(A[1][1], h1, ua[1]));
  const float zf0 = fmaf(A[2][0], h0, fmaf(A[2][1], h1, ua[2]));
  const float zf1 = fmaf(A[3][0], h0, fmaf(A[3][1], h1, ua[3]));
  const float zg0 = fmaf(A[4][0], h0, fmaf(A[4][1], h1, ub[0]));
  const float zg1 = fmaf(A[5][0], h0, fmaf(A[5][1], h1, ub[1]));
  const float zo0 = fmaf(A[6][0], h0, fmaf(A[6][1], h1, ub[2]));
  const float zo1 = fmaf(A[7][0], h0, fmaf(A[7][1], h1, ub[3]));

  const float si0 = sigm2(zi0), si1 = sigm2(zi1);
  const float sf0 = sigm2(zf0), sf1 = sigm2(zf1);
  const float tg0 = tanh2(zg0), tg1 = tanh2(zg1);
  const float so0 = sigm2(zo0), so1 = sigm2(zo1);

  c0 = fmaf(sf0, c0, si0 * tg0);
  c1 = fmaf(sf1, c1, si1 * tg1);
  h0 = so0 * tanh2(N2LOG2E * c0);
  h1 = so1 * tanh2(N2LOG2E * c1);

  // p2 (H=1)
  const float yi = fmaf(A2[0], h2, uc[0]);
  const float yf = fmaf(A2[1], h2, uc[1]);
  const float yg = fmaf(A2[2], h2, uc[2]);
  const float yo = fmaf(A2[3], h2, uc[3]);
  c2 = fmaf(sigm2(yf), c2, sigm2(yi) * tanh2(yg));
  h2 = sigm2(yo) * tanh2(N2LOG2E * c2);

  // adjust = nw - p1 + p2 (masked: past length p1=p2=0)
  const bool v = t < len;
  const float a0 = v ? (nw[0] - h0 + h2) : nw[0];
  const float a1 = v ? (nw[1] - h1 + h2) : nw[1];
  *(float2*)(o + (size_t)t * 2) = make_float2(a0, a1);
}

// Kernel B: both recurrences + fused adjust. One lane per batch element.
// ws is [T][B][16]: per step the wave reads one contiguous 4KB block (coalesced).
// Chunked double-buffer: issue the next chunk's 16 loads as a group, then
// sched_barrier(0) pins them above the current chunk's compute (prevents the
// scheduler from sinking the prefetch, which is what collapsed the r3 pipeline).
// The compiler inserts its own counted vmcnt before the next chunk's first use.
__global__ __launch_bounds__(64) void lstm_kernel(
    const float* __restrict__ ws, const int* __restrict__ lengths,
    const float* __restrict__ Whh1, const float* __restrict__ Whh2,
    float* __restrict__ out_adj)
{
  const int b = threadIdx.x;  // 0..63

  float A[8][2];
#pragma unroll
  for (int k = 0; k < 8; ++k) {
    const float s = (k == 4 || k == 5) ? N2LOG2E : NLOG2E;
    A[k][0] = s * Whh1[2 * k];
    A[k][1] = s * Whh1[2 * k + 1];
  }
  float A2[4];
#pragma unroll
  for (int k = 0; k < 4; ++k) {
    const float s = (k == 2) ? N2LOG2E : NLOG2E;
    A2[k] = s * Whh2[k];
  }

  const int len = lengths[b];
  const float* base = ws + b * 16;          // lane's column in [T][B][16]
  float* o = out_adj + (size_t)b * TT * 2;

  float h0 = 0.f, h1 = 0.f, c0 = 0.f, c1 = 0.f;  // p1 state (H=2)
  float h2 = 0.f, c2 = 0.f;                       // p2 state (H=1)

  f32x4 Abuf[4 * CH], Bbuf[4 * CH];

  // prologue: chunk 0 -> Abuf
#pragma unroll
  for (int j = 0; j < CH; ++j) {
    const float* p = base + (size_t)j * (16 * BB);
    Abuf[4 * j + 0] = *(const f32x4*)(p);
    Abuf[4 * j + 1] = *(const f32x4*)(p + 4);
    Abuf[4 * j + 2] = *(const f32x4*)(p + 8);
    Abuf[4 * j + 3] = *(const f32x4*)(p + 12);
  }
  __builtin_amdgcn_sched_barrier(0);

  for (int t0 = 0; t0 < TT; t0 += 2 * CH) {
    // issue loads: chunk t0+CH -> Bbuf
#pragma unroll
    for (int j = 0; j < CH; ++j) {
      const float* p = base + (size_t)(t0 + CH + j) * (16 * BB);
      Bbuf[4 * j + 0] = *(const f32x4*)(p);
      Bbuf[4 * j + 1] = *(const f32x4*)(p + 4);
      Bbuf[4 * j + 2] = *(const f32x4*)(p + 8);
      Bbuf[4 * j + 3] = *(const f32x4*)(p + 12);
    }
    __builtin_amdgcn_sched_barrier(0);

    // compute chunk t0 from Abuf
#pragma unroll
    for (int j = 0; j < CH; ++j)
      lstm_step(Abuf[4 * j + 0], Abuf[4 * j + 1], Abuf[4 * j + 2], Abuf[4 * j + 3],
                A, A2, h0, h1, c0, c1, h2, c2, t0 + j, len, o);
    __builtin_amdgcn_sched_barrier(0);

    // issue loads: chunk t0+2*CH -> Abuf (clamped at the tail; reload of t=0 is harmless)
#pragma unroll
    for (int j = 0; j < CH; ++j) {
      const int tn = t0 + 2 * CH + j;
      const float* p = base + (size_t)(tn < TT ? tn : 0) * (16 * BB);
      Abuf[4 * j + 0] = *(const f32x4*)(p);
      Abuf[4 * j + 1] = *(const f32x4*)(p + 4);
      Abuf[4 * j + 2] = *(const f32x4*)(p + 8);
      Abuf[4 * j + 3] = *(const f32x4*)(p + 12);
    }
    __builtin_amdgcn_sched_barrier(0);

    // compute chunk t0+CH from Bbuf
#pragma unroll
    for (int j = 0; j < CH; ++j)
      lstm_step(Bbuf[4 * j + 0], Bbuf[4 * j + 1], Bbuf[4 * j + 2], Bbuf[4 * j + 3],
                A, A2, h0, h1, c0, c1, h2, c2, t0 + CH + j, len, o);
    __builtin_amdgcn_sched_barrier(0);
  }
}

extern "C" void kernel_launch(void* const* d_in, const int* in_sizes, int n_in,
                              void* d_out, int out_size, void* d_ws, size_t ws_size,
                              hipStream_t stream) {
  const float* x            = (const float*)d_in[0];
  const int* wt             = (const int*)d_in[1];
  const int* lengths        = (const int*)d_in[2];
  const float* Wnw          = (const float*)d_in[3];
  const float* bnw          = (const float*)d_in[4];
  const float* Ww           = (const float*)d_in[5];
  const float* bw           = (const float*)d_in[6];
  const float* Wih1         = (const float*)d_in[7];
  const float* Whh1         = (const float*)d_in[8];
  const float* bih1         = (const float*)d_in[9];
  const float* bhh1         = (const float*)d_in[10];
  const float* Wih2         = (const float*)d_in[11];
  const float* Whh2         = (const float*)d_in[12];
  const float* bih2         = (const float*)d_in[13];
  const float* bhh2         = (const float*)d_in[14];

  float* out_nw  = (float*)d_out;                       // [B,T,2]
  float* out_adj = (float*)d_out + (size_t)NROWS * 2;   // [B,T,2]
  float* ws      = (float*)d_ws;                        // [T][B][16] floats = 8 MB

  proj_kernel<<<1024, 256, 0, stream>>>(x, wt, Wnw, bnw, Ww, bw,
                                        Wih1, bih1, bhh1, Wih2, bih2, bhh2,
                                        out_nw, ws);
  lstm_kernel<<<1, 64, 0, stream>>>(ws, lengths, Whh1, Whh2, out_adj);
}